// Round 7
// baseline (125.048 us; speedup 1.0000x reference)
//
#include <hip/hip_runtime.h>
#include <cstdint>

#define BB   16
#define NN   1024
#define FIN  128
#define FOUT 64
#define ALPHA_S 0.2f

typedef float    f32x4 __attribute__((ext_vector_type(4)));
typedef _Float16 half8 __attribute__((ext_vector_type(8)));
typedef _Float16 half4 __attribute__((ext_vector_type(4)));

// ---------------------------------------------------------------------------
// Kernel 1 (MFMA): h = inp @ W via f16 hi/lo 3-term MFMA (rel err ~2^-22);
// s1 = h.a1, s2 = h.a2 (fp32); hT (f16, hi only) in layout hT[b][j>>5][f][j&31].
// 1024 blocks x 256 thr; block = 16 rows; wave w = 16-col tile.
// ---------------------------------------------------------------------------
__global__ __launch_bounds__(256) void k_proj(const float* __restrict__ inp,
                                              const float* __restrict__ W,
                                              const float* __restrict__ a,
                                              _Float16* __restrict__ hT,
                                              float* __restrict__ s1,
                                              float* __restrict__ s2){
  __shared__ float red1[4][16];
  __shared__ float red2[4][16];
  const int t = threadIdx.x;
  const int w = t >> 6, lane = t & 63;
  const int m16 = lane & 15, g = lane >> 4;
  const int i0 = blockIdx.x * 16;
  const int b  = i0 >> 10;
  const int j0 = i0 & 1023;
  const int c0 = w * 16;

  const float* arow = inp + (size_t)(i0 + m16) * FIN;

  f32x4 acc = {0.f, 0.f, 0.f, 0.f};
  #pragma unroll
  for (int kk = 0; kk < 4; ++kk){
    const int kbase = kk * 32 + g * 8;
    float4 av0 = *(const float4*)(arow + kbase);
    float4 av1 = *(const float4*)(arow + kbase + 4);
    const float av[8] = {av0.x, av0.y, av0.z, av0.w, av1.x, av1.y, av1.z, av1.w};
    half8 ah, al;
    #pragma unroll
    for (int j = 0; j < 8; ++j){
      _Float16 h = (_Float16)av[j];
      ah[j] = h;
      al[j] = (_Float16)(av[j] - (float)h);
    }
    half8 bh, bl;
    #pragma unroll
    for (int j = 0; j < 8; ++j){
      float wv = W[(kbase + j) * FOUT + c0 + m16];   // L1-hot (W = 32 KB)
      _Float16 h = (_Float16)wv;
      bh[j] = h;
      bl[j] = (_Float16)(wv - (float)h);
    }
    acc = __builtin_amdgcn_mfma_f32_16x16x32_f16(ah, bh, acc, 0, 0, 0);
    acc = __builtin_amdgcn_mfma_f32_16x16x32_f16(ah, bl, acc, 0, 0, 0);
    acc = __builtin_amdgcn_mfma_f32_16x16x32_f16(al, bh, acc, 0, 0, 0);
  }

  const float a1c = a[c0 + m16];
  const float a2c = a[FOUT + c0 + m16];
  f32x4 p1, p2;
  #pragma unroll
  for (int q = 0; q < 4; ++q){ p1[q] = acc[q] * a1c; p2[q] = acc[q] * a2c; }
  #pragma unroll
  for (int off = 1; off < 16; off <<= 1){
    #pragma unroll
    for (int q = 0; q < 4; ++q){
      p1[q] += __shfl_xor(p1[q], off, 64);
      p2[q] += __shfl_xor(p2[q], off, 64);
    }
  }
  if (m16 == 0){
    #pragma unroll
    for (int q = 0; q < 4; ++q){
      red1[w][g * 4 + q] = p1[q];
      red2[w][g * 4 + q] = p2[q];
    }
  }

  half4 hv;
  #pragma unroll
  for (int q = 0; q < 4; ++q) hv[q] = (_Float16)acc[q];
  size_t idx = (size_t)b * 65536 + (size_t)(j0 >> 5) * 2048
             + (size_t)(c0 + m16) * 32 + (size_t)(j0 & 31) + (size_t)g * 4;
  *(half4*)(hT + idx) = hv;

  __syncthreads();
  if (t < 16){
    s1[i0 + t] = red1[0][t] + red1[1][t] + red1[2][t] + red1[3][t];
    s2[i0 + t] = red2[0][t] + red2[1][t] + red2[2][t] + red2[3][t];
  }
}

// ---------------------------------------------------------------------------
// Kernel 2: flash-split attention partials. ONE WAVE per block, no LDS, no
// barriers. Block = (batch, 16-row tile, j-quarter of 256). Grid = 4096.
// Emits un-normalized C_q (fp32 16x64), per-row m_q (quarter score max via
// monotone leaky trick) and l_q. Empty quarter -> p==1, m_q = -3e38 (killed
// by combiner weights unless ALL quarters empty -> uniform, matching ref).
// ---------------------------------------------------------------------------
__global__ __launch_bounds__(64) void k_attn4(const int* __restrict__ adj,
                                              const _Float16* __restrict__ hT,
                                              const float* __restrict__ s1,
                                              const float* __restrict__ s2,
                                              float* __restrict__ pC,
                                              float* __restrict__ pML){
  const int lane = threadIdx.x;
  const int m16 = lane & 15, g = lane >> 4;
  const int tile = blockIdx.x >> 2, q = blockIdx.x & 3;
  const int b  = tile >> 6;
  const int i0 = (tile & 63) * 16;
  const int jb = q * 256;

  const float s1i = s1[b * NN + i0 + m16];
  const float* s2b = s2 + b * NN + jb;
  const int* arow = adj + ((size_t)(b * NN + i0 + m16)) * NN + jb + g * 8;

  // ---- bitmask + quarter neighbor-max of s2 (adj streamed in 2 halves) ----
  unsigned mask_lo = 0u, mask_hi = 0u;
  float mxp = -3.0e38f;
  #pragma unroll
  for (int h = 0; h < 2; ++h){
    int4 A0[4], A1[4];
    #pragma unroll
    for (int k = 0; k < 4; ++k){
      A0[k] = *(const int4*)(arow + (h * 4 + k) * 32);
      A1[k] = *(const int4*)(arow + (h * 4 + k) * 32 + 4);
    }
    unsigned accb = 0u;
    #pragma unroll
    for (int k = 0; k < 4; ++k){
      const int kk = h * 4 + k;
      float4 sA = *(const float4*)(s2b + kk * 32 + g * 8);
      float4 sB = *(const float4*)(s2b + kk * 32 + g * 8 + 4);
      unsigned bits = 0u;
      bits |= (A0[k].x > 0) ? 1u   : 0u;  mxp = fmaxf(mxp, A0[k].x > 0 ? sA.x : -3.0e38f);
      bits |= (A0[k].y > 0) ? 2u   : 0u;  mxp = fmaxf(mxp, A0[k].y > 0 ? sA.y : -3.0e38f);
      bits |= (A0[k].z > 0) ? 4u   : 0u;  mxp = fmaxf(mxp, A0[k].z > 0 ? sA.z : -3.0e38f);
      bits |= (A0[k].w > 0) ? 8u   : 0u;  mxp = fmaxf(mxp, A0[k].w > 0 ? sA.w : -3.0e38f);
      bits |= (A1[k].x > 0) ? 16u  : 0u;  mxp = fmaxf(mxp, A1[k].x > 0 ? sB.x : -3.0e38f);
      bits |= (A1[k].y > 0) ? 32u  : 0u;  mxp = fmaxf(mxp, A1[k].y > 0 ? sB.y : -3.0e38f);
      bits |= (A1[k].z > 0) ? 64u  : 0u;  mxp = fmaxf(mxp, A1[k].z > 0 ? sB.z : -3.0e38f);
      bits |= (A1[k].w > 0) ? 128u : 0u;  mxp = fmaxf(mxp, A1[k].w > 0 ? sB.w : -3.0e38f);
      accb |= bits << (k * 8);
    }
    if (h == 0) mask_lo = accb; else mask_hi = accb;
  }

  // row max over the 4 g-lanes sharing m16 (wave-local; rows are per-m16)
  mxp = fmaxf(mxp, __shfl_xor(mxp, 16, 64));
  mxp = fmaxf(mxp, __shfl_xor(mxp, 32, 64));
  const bool empty = (mxp < -1.0e38f);
  const float xm = s1i + mxp;
  const float mrow = fmaxf(xm, ALPHA_S * xm);   // exact quarter score max

  // ---- p in A-frag layout -> 4 col-tile MFMAs ----
  f32x4 acc0 = {0,0,0,0}, acc1 = {0,0,0,0}, acc2 = {0,0,0,0}, acc3 = {0,0,0,0};
  float psum = 0.f;
  const _Float16* bhp = hT + (size_t)b * 65536 + (size_t)(jb >> 5) * 2048
                      + (size_t)m16 * 32 + (size_t)g * 8;

  #pragma unroll
  for (int kk = 0; kk < 8; ++kk){
    float4 sA = *(const float4*)(s2b + kk * 32 + g * 8);
    float4 sB = *(const float4*)(s2b + kk * 32 + g * 8 + 4);
    const unsigned bits = ((kk < 4) ? (mask_lo >> (kk * 8)) : (mask_hi >> ((kk - 4) * 8))) & 0xffu;
    const float sv[8] = {sA.x, sA.y, sA.z, sA.w, sB.x, sB.y, sB.z, sB.w};
    half8 af;
    #pragma unroll
    for (int u = 0; u < 8; ++u){
      float x = s1i + sv[u];
      float e = fmaxf(x, ALPHA_S * x);
      float p = __expf(e - mrow);                 // <= 1 within quarter
      p = ((bits >> u) & 1u) ? p : 0.0f;
      p = empty ? 1.0f : p;                       // uniform placeholder
      af[u] = (_Float16)p;
      psum += (float)af[u];                       // denom == numerator dtype
    }
    half8 b0 = *(const half8*)(bhp + kk * 2048);
    half8 b1 = *(const half8*)(bhp + kk * 2048 + 512);
    half8 b2 = *(const half8*)(bhp + kk * 2048 + 1024);
    half8 b3 = *(const half8*)(bhp + kk * 2048 + 1536);
    acc0 = __builtin_amdgcn_mfma_f32_16x16x32_f16(af, b0, acc0, 0, 0, 0);
    acc1 = __builtin_amdgcn_mfma_f32_16x16x32_f16(af, b1, acc1, 0, 0, 0);
    acc2 = __builtin_amdgcn_mfma_f32_16x16x32_f16(af, b2, acc2, 0, 0, 0);
    acc3 = __builtin_amdgcn_mfma_f32_16x16x32_f16(af, b3, acc3, 0, 0, 0);
  }

  psum += __shfl_xor(psum, 16, 64);
  psum += __shfl_xor(psum, 32, 64);

  // ---- store partials (no normalization here) ----
  float* pc = pC + (size_t)blockIdx.x * 1024;
  #pragma unroll
  for (int qr = 0; qr < 4; ++qr){                // C: row=g*4+qr, col=c*16+m16
    pc[(g * 4 + qr) * 64 +  0 + m16] = acc0[qr];
    pc[(g * 4 + qr) * 64 + 16 + m16] = acc1[qr];
    pc[(g * 4 + qr) * 64 + 32 + m16] = acc2[qr];
    pc[(g * 4 + qr) * 64 + 48 + m16] = acc3[qr];
  }
  if (g == 0){
    pML[(size_t)blockIdx.x * 32 + m16]      = empty ? -3.0e38f : mrow;
    pML[(size_t)blockIdx.x * 32 + 16 + m16] = psum;
  }
}

// ---------------------------------------------------------------------------
// Kernel 3: flash combine of the 4 j-quarters + ELU + store.
// 1024 blocks x 64 thr; lane = output col, loop over 16 rows.
// ---------------------------------------------------------------------------
__global__ __launch_bounds__(64) void k_comb(const float* __restrict__ pC,
                                             const float* __restrict__ pML,
                                             float* __restrict__ out){
  const int c = threadIdx.x;
  const int tile = blockIdx.x;
  const int b  = tile >> 6;
  const int i0 = (tile & 63) * 16;
  const size_t base = (size_t)tile * 4;
  const float* ml0 = pML + (base + 0) * 32;
  const float* ml1 = pML + (base + 1) * 32;
  const float* ml2 = pML + (base + 2) * 32;
  const float* ml3 = pML + (base + 3) * 32;
  const float* c0p = pC + (base + 0) * 1024 + c;
  const float* c1p = pC + (base + 1) * 1024 + c;
  const float* c2p = pC + (base + 2) * 1024 + c;
  const float* c3p = pC + (base + 3) * 1024 + c;

  #pragma unroll 4
  for (int r = 0; r < 16; ++r){
    float m0 = ml0[r], m1 = ml1[r], m2 = ml2[r], m3 = ml3[r];
    float l0 = ml0[16 + r], l1 = ml1[16 + r], l2 = ml2[16 + r], l3 = ml3[16 + r];
    float C0 = c0p[r * 64], C1 = c1p[r * 64], C2 = c2p[r * 64], C3 = c3p[r * 64];
    float M = fmaxf(fmaxf(m0, m1), fmaxf(m2, m3));
    float w0 = __expf(m0 - M);                  // all-empty: 0-0 -> w=1 each
    float w1 = __expf(m1 - M);
    float w2 = __expf(m2 - M);
    float w3 = __expf(m3 - M);
    float den = fmaf(w0, l0, fmaf(w1, l1, fmaf(w2, l2, w3 * l3)));
    float num = fmaf(w0, C0, fmaf(w1, C1, fmaf(w2, C2, w3 * C3)));
    float v = num / den;
    out[((size_t)(b * NN + i0 + r)) * FOUT + c] = v > 0.f ? v : __expf(v) - 1.0f;
  }
}

extern "C" void kernel_launch(void* const* d_in, const int* in_sizes, int n_in,
                              void* d_out, int out_size, void* d_ws, size_t ws_size,
                              hipStream_t stream) {
  (void)in_sizes; (void)n_in; (void)out_size; (void)ws_size;
  const float* inp = (const float*)d_in[0];   // (16,1024,128) fp32
  const int*   adj = (const int*)d_in[1];     // (16,1024,1024) int32
  const float* W   = (const float*)d_in[2];   // (128,64) fp32
  const float* a   = (const float*)d_in[3];   // (128,1) fp32
  float* outp = (float*)d_out;                // (16,1024,64) fp32

  _Float16* hT = (_Float16*)d_ws;                      // 2 MB (hi only)
  float* s1  = (float*)(hT + (size_t)BB * 65536);      // 64 KB
  float* s2  = s1 + BB * NN;                           // 64 KB
  float* pC  = s2 + BB * NN;                           // 4096*1024 f = 16 MB
  float* pML = pC + (size_t)4096 * 1024;               // 512 KB

  k_proj <<<BB * NN / 16,    256, 0, stream>>>(inp, W, a, hT, s1, s2);
  k_attn4<<<BB * (NN/16)*4,   64, 0, stream>>>(adj, hT, s1, s2, pC, pML);
  k_comb <<<BB * (NN/16),     64, 0, stream>>>(pC, pML, outp);
}

// Round 8
// 117.516 us; speedup vs baseline: 1.0641x; 1.0641x over previous
//
#include <hip/hip_runtime.h>
#include <cstdint>

#define BB   16
#define NN   1024
#define FIN  128
#define FOUT 64
#define ALPHA_S 0.2f

typedef float    f32x4 __attribute__((ext_vector_type(4)));
typedef _Float16 half8 __attribute__((ext_vector_type(8)));
typedef _Float16 half4 __attribute__((ext_vector_type(4)));

__device__ inline float wave_max(float v){
  #pragma unroll
  for (int off = 32; off; off >>= 1) v = fmaxf(v, __shfl_xor(v, off, 64));
  return v;
}

// ---------------------------------------------------------------------------
// Kernel 1 (unchanged from R6): h = inp @ W via f16 hi/lo 3-term MFMA;
// s1 = h.a1, s2 = h.a2 (fp32); hT (f16 hi) in layout hT[b][j>>5][f][j&31].
// ---------------------------------------------------------------------------
__global__ __launch_bounds__(256) void k_proj(const float* __restrict__ inp,
                                              const float* __restrict__ W,
                                              const float* __restrict__ a,
                                              _Float16* __restrict__ hT,
                                              float* __restrict__ s1,
                                              float* __restrict__ s2){
  __shared__ float red1[4][16];
  __shared__ float red2[4][16];
  const int t = threadIdx.x;
  const int w = t >> 6, lane = t & 63;
  const int m16 = lane & 15, g = lane >> 4;
  const int i0 = blockIdx.x * 16;
  const int b  = i0 >> 10;
  const int j0 = i0 & 1023;
  const int c0 = w * 16;

  const float* arow = inp + (size_t)(i0 + m16) * FIN;

  f32x4 acc = {0.f, 0.f, 0.f, 0.f};
  #pragma unroll
  for (int kk = 0; kk < 4; ++kk){
    const int kbase = kk * 32 + g * 8;
    float4 av0 = *(const float4*)(arow + kbase);
    float4 av1 = *(const float4*)(arow + kbase + 4);
    const float av[8] = {av0.x, av0.y, av0.z, av0.w, av1.x, av1.y, av1.z, av1.w};
    half8 ah, al;
    #pragma unroll
    for (int j = 0; j < 8; ++j){
      _Float16 h = (_Float16)av[j];
      ah[j] = h;
      al[j] = (_Float16)(av[j] - (float)h);
    }
    half8 bh, bl;
    #pragma unroll
    for (int j = 0; j < 8; ++j){
      float wv = W[(kbase + j) * FOUT + c0 + m16];   // L1-hot (W = 32 KB)
      _Float16 h = (_Float16)wv;
      bh[j] = h;
      bl[j] = (_Float16)(wv - (float)h);
    }
    acc = __builtin_amdgcn_mfma_f32_16x16x32_f16(ah, bh, acc, 0, 0, 0);
    acc = __builtin_amdgcn_mfma_f32_16x16x32_f16(ah, bl, acc, 0, 0, 0);
    acc = __builtin_amdgcn_mfma_f32_16x16x32_f16(al, bh, acc, 0, 0, 0);
  }

  const float a1c = a[c0 + m16];
  const float a2c = a[FOUT + c0 + m16];
  f32x4 p1, p2;
  #pragma unroll
  for (int q = 0; q < 4; ++q){ p1[q] = acc[q] * a1c; p2[q] = acc[q] * a2c; }
  #pragma unroll
  for (int off = 1; off < 16; off <<= 1){
    #pragma unroll
    for (int q = 0; q < 4; ++q){
      p1[q] += __shfl_xor(p1[q], off, 64);
      p2[q] += __shfl_xor(p2[q], off, 64);
    }
  }
  if (m16 == 0){
    #pragma unroll
    for (int q = 0; q < 4; ++q){
      red1[w][g * 4 + q] = p1[q];
      red2[w][g * 4 + q] = p2[q];
    }
  }

  half4 hv;
  #pragma unroll
  for (int q = 0; q < 4; ++q) hv[q] = (_Float16)acc[q];
  size_t idx = (size_t)b * 65536 + (size_t)(j0 >> 5) * 2048
             + (size_t)(c0 + m16) * 32 + (size_t)(j0 & 31) + (size_t)g * 4;
  *(half4*)(hT + idx) = hv;

  __syncthreads();
  if (t < 16){
    s1[i0 + t] = red1[0][t] + red1[1][t] + red1[2][t] + red1[3][t];
    s2[i0 + t] = red2[0][t] + red2[1][t] + red2[2][t] + red2[3][t];
  }
}

// ---------------------------------------------------------------------------
// Kernel 2: single-pass fused GAT attention, COALESCED adj + ballot transpose.
// 1024 blocks x 256 thr. Block = (batch, 16-row tile). Wave w owns j-range
// [w*256, w*256+256) and all 64 output cols.
// adj: thread t loads cols jb+4t..4t+3 for all 16 rows (each instruction =
// 4 KB contiguous). Mask redistributed to A-fragment order via 4 ballots/row
// (SGPR broadcast, no LDS). Masked row-max folded into the same loop.
// __launch_bounds__(256,3): ~168 VGPR cap so all 16 row loads stay in flight.
// ---------------------------------------------------------------------------
__global__ __launch_bounds__(256, 3) void k_attn(const int* __restrict__ adj,
                                                 const _Float16* __restrict__ hT,
                                                 const float* __restrict__ s1,
                                                 const float* __restrict__ s2,
                                                 float* __restrict__ out){
  __shared__ float s2_s[NN];            // 4 KB
  __shared__ float redmax[4][16];
  __shared__ float redl[4][16];
  __shared__ float csum[4][1088];       // ~17 KB

  const int t = threadIdx.x;
  const int w = t >> 6, lane = t & 63;
  const int m16 = lane & 15, g = lane >> 4;
  const int b  = blockIdx.x >> 6;
  const int i0 = (blockIdx.x & 63) * 16;
  const int jb = w * 256;

  // own 4 cols' s2 (registers) + stage for Phase-2 broadcast reads
  float4 s2own = *(const float4*)(s2 + b * NN + jb + lane * 4);
  *(float4*)&s2_s[jb + lane * 4] = s2own;

  const float s1i = s1[b * NN + i0 + m16];

  // ---- coalesced adj: 16 x 4KB-contiguous int4 loads, all in flight ----
  const int* abase = adj + ((size_t)(b * NN + i0)) * NN + jb + lane * 4;
  int4 A[16];
  #pragma unroll
  for (int r = 0; r < 16; ++r) A[r] = *(const int4*)(abase + (size_t)r * NN);

  // ---- per-row ballots (mask transpose) + masked row-max of s2 ----
  unsigned long long bal0 = 0, bal1 = 0, bal2 = 0, bal3 = 0;
  float rowmax_mine = -3.0e38f;
  #pragma unroll
  for (int r = 0; r < 16; ++r){
    const int4 a4 = A[r];
    unsigned long long c0 = __ballot(a4.x > 0);
    unsigned long long c1 = __ballot(a4.y > 0);
    unsigned long long c2 = __ballot(a4.z > 0);
    unsigned long long c3 = __ballot(a4.w > 0);
    float mm = -3.0e38f;
    mm = fmaxf(mm, a4.x > 0 ? s2own.x : -3.0e38f);
    mm = fmaxf(mm, a4.y > 0 ? s2own.y : -3.0e38f);
    mm = fmaxf(mm, a4.z > 0 ? s2own.z : -3.0e38f);
    mm = fmaxf(mm, a4.w > 0 ? s2own.w : -3.0e38f);
    mm = wave_max(mm);
    const bool mine = (r == m16);
    bal0 = mine ? c0 : bal0;
    bal1 = mine ? c1 : bal1;
    bal2 = mine ? c2 : bal2;
    bal3 = mine ? c3 : bal3;
    rowmax_mine = mine ? mm : rowmax_mine;
  }

  if (g == 0) redmax[w][m16] = rowmax_mine;
  __syncthreads();
  float mxg = fmaxf(fmaxf(redmax[0][m16], redmax[1][m16]),
                    fmaxf(redmax[2][m16], redmax[3][m16]));
  const bool empty = (mxg < -1.0e38f);
  const float xm = s1i + mxg;
  const float mrow = fmaxf(xm, ALPHA_S * xm);   // exact row max (monotone)

  // ---- Phase 2: p (A-frag, registers) -> 4 col-tile MFMAs ----
  f32x4 acc0 = {0,0,0,0}, acc1 = {0,0,0,0}, acc2 = {0,0,0,0}, acc3 = {0,0,0,0};
  float psum = 0.f;
  const _Float16* bhp = hT + (size_t)b * 65536 + (size_t)(jb >> 5) * 2048
                      + (size_t)m16 * 32 + (size_t)g * 8;

  #pragma unroll
  for (int kk = 0; kk < 8; ++kk){
    float4 sA = *(const float4*)&s2_s[jb + kk * 32 + g * 8];
    float4 sB = *(const float4*)&s2_s[jb + kk * 32 + g * 8 + 4];
    const int sh = kk * 8 + g * 2;
    // bit u of bits8 = adjacency of col jb + kk*32 + g*8 + u
    const unsigned bits8 =
        ((unsigned)(bal0 >> sh)       & 1u)        |
       (((unsigned)(bal1 >> sh)       & 1u) << 1)  |
       (((unsigned)(bal2 >> sh)       & 1u) << 2)  |
       (((unsigned)(bal3 >> sh)       & 1u) << 3)  |
       (((unsigned)(bal0 >> (sh + 1)) & 1u) << 4)  |
       (((unsigned)(bal1 >> (sh + 1)) & 1u) << 5)  |
       (((unsigned)(bal2 >> (sh + 1)) & 1u) << 6)  |
       (((unsigned)(bal3 >> (sh + 1)) & 1u) << 7);
    const float sv[8] = {sA.x, sA.y, sA.z, sA.w, sB.x, sB.y, sB.z, sB.w};
    half8 af;
    #pragma unroll
    for (int u = 0; u < 8; ++u){
      float x = s1i + sv[u];
      float e = fmaxf(x, ALPHA_S * x);
      float p = __expf(e - mrow);                 // <= 1
      p = ((bits8 >> u) & 1u) ? p : 0.0f;
      p = empty ? 1.0f : p;                       // all-masked row -> uniform
      af[u] = (_Float16)p;
      psum += (float)af[u];                       // denom == numerator dtype
    }
    half8 b0 = *(const half8*)(bhp + kk * 2048);
    half8 b1 = *(const half8*)(bhp + kk * 2048 + 512);
    half8 b2 = *(const half8*)(bhp + kk * 2048 + 1024);
    half8 b3 = *(const half8*)(bhp + kk * 2048 + 1536);
    acc0 = __builtin_amdgcn_mfma_f32_16x16x32_f16(af, b0, acc0, 0, 0, 0);
    acc1 = __builtin_amdgcn_mfma_f32_16x16x32_f16(af, b1, acc1, 0, 0, 0);
    acc2 = __builtin_amdgcn_mfma_f32_16x16x32_f16(af, b2, acc2, 0, 0, 0);
    acc3 = __builtin_amdgcn_mfma_f32_16x16x32_f16(af, b3, acc3, 0, 0, 0);
  }

  // ---- epilogue: cross-wave l and C reduction, ELU, store ----
  psum += __shfl_xor(psum, 16, 64);
  psum += __shfl_xor(psum, 32, 64);
  if (g == 0) redl[w][m16] = psum;

  #pragma unroll
  for (int q = 0; q < 4; ++q){                   // C: row = g*4+q, col = c*16+m16
    csum[w][(g * 4 + q) * 68 +  0 + m16] = acc0[q];
    csum[w][(g * 4 + q) * 68 + 16 + m16] = acc1[q];
    csum[w][(g * 4 + q) * 68 + 32 + m16] = acc2[q];
    csum[w][(g * 4 + q) * 68 + 48 + m16] = acc3[q];
  }
  __syncthreads();

  const int r  = t >> 4;                         // 0..15
  const int c4 = (t & 15) * 4;                   // 0..60
  f32x4 sum = *(const f32x4*)&csum[0][r * 68 + c4];
  sum += *(const f32x4*)&csum[1][r * 68 + c4];
  sum += *(const f32x4*)&csum[2][r * 68 + c4];
  sum += *(const f32x4*)&csum[3][r * 68 + c4];
  const float linv = 1.0f / (redl[0][r] + redl[1][r] + redl[2][r] + redl[3][r]);
  f32x4 o;
  #pragma unroll
  for (int u = 0; u < 4; ++u){
    float v = sum[u] * linv;
    o[u] = v > 0.f ? v : __expf(v) - 1.0f;       // ELU (alpha=1)
  }
  *(f32x4*)(out + ((size_t)(b * NN + i0 + r)) * FOUT + c4) = o;
}

extern "C" void kernel_launch(void* const* d_in, const int* in_sizes, int n_in,
                              void* d_out, int out_size, void* d_ws, size_t ws_size,
                              hipStream_t stream) {
  (void)in_sizes; (void)n_in; (void)out_size; (void)ws_size;
  const float* inp = (const float*)d_in[0];   // (16,1024,128) fp32
  const int*   adj = (const int*)d_in[1];     // (16,1024,1024) int32
  const float* W   = (const float*)d_in[2];   // (128,64) fp32
  const float* a   = (const float*)d_in[3];   // (128,1) fp32
  float* outp = (float*)d_out;                // (16,1024,64) fp32

  _Float16* hT = (_Float16*)d_ws;                      // 2 MB (hi only)
  float* s1 = (float*)(hT + (size_t)BB * 65536);       // 64 KB
  float* s2 = s1 + BB * NN;                            // 64 KB

  k_proj<<<BB * NN / 16, 256, 0, stream>>>(inp, W, a, hT, s1, s2);
  k_attn<<<BB * (NN / 16), 256, 0, stream>>>(adj, hT, s1, s2, outp);
}

// Round 9
// 116.832 us; speedup vs baseline: 1.0703x; 1.0058x over previous
//
#include <hip/hip_runtime.h>
#include <cstdint>

#define BB   16
#define NN   1024
#define FIN  128
#define FOUT 64
#define ALPHA_S 0.2f

typedef float    f32x4 __attribute__((ext_vector_type(4)));
typedef _Float16 half8 __attribute__((ext_vector_type(8)));
typedef _Float16 half4 __attribute__((ext_vector_type(4)));

// ---------------------------------------------------------------------------
// Kernel 1: fused (a) adj -> bitmask pack (pure coalesced stream, the 67 MB
// long pole) and (b) h = inp @ W via f16 hi/lo MFMA; s1 = h.a1, s2 = h.a2;
// hT (f16 hi) in layout hT[b][j>>5][f][j&31].
// 1024 blocks x 256 thr; block = 16 global rows (i0 = blockIdx.x*16).
// Mask layout: mask[grow][w] (32 uint32/row), bit u of word w = adj[grow][32w+u].
// ---------------------------------------------------------------------------
__global__ __launch_bounds__(256) void k_proj(const float* __restrict__ inp,
                                              const float* __restrict__ W,
                                              const float* __restrict__ a,
                                              const int* __restrict__ adj,
                                              _Float16* __restrict__ hT,
                                              float* __restrict__ s1,
                                              float* __restrict__ s2,
                                              uint32_t* __restrict__ mask){
  __shared__ float red1[4][16];
  __shared__ float red2[4][16];
  const int t = threadIdx.x;
  const int w = t >> 6, lane = t & 63;
  const int m16 = lane & 15, g = lane >> 4;
  const int i0 = blockIdx.x * 16;          // global row base (b*1024 + local)
  const int b  = i0 >> 10;
  const int j0 = i0 & 1023;
  const int c0 = w * 16;

  // ---- (a) adj -> bitmask: wave w packs rows i0 + w*4 .. +3 ----
  #pragma unroll
  for (int q = 0; q < 4; ++q){
    const int grow = i0 + w * 4 + q;
    const int* arow = adj + (size_t)grow * NN;
    uint32_t myword = 0u;
    #pragma unroll
    for (int c = 0; c < 16; ++c){
      int v = arow[c * 64 + lane];                     // coalesced 256 B
      unsigned long long bal = __ballot(v > 0);        // bit l = j 64c+l
      uint32_t half = (lane & 1) ? (uint32_t)(bal >> 32) : (uint32_t)bal;
      myword = ((lane >> 1) == c) ? half : myword;
    }
    if (lane < 32) mask[(size_t)grow * 32 + lane] = myword;  // 128 B coalesced
  }

  // ---- (b) projection (identical to R6) ----
  const float* arowf = inp + (size_t)(i0 + m16) * FIN;

  f32x4 acc = {0.f, 0.f, 0.f, 0.f};
  #pragma unroll
  for (int kk = 0; kk < 4; ++kk){
    const int kbase = kk * 32 + g * 8;
    float4 av0 = *(const float4*)(arowf + kbase);
    float4 av1 = *(const float4*)(arowf + kbase + 4);
    const float av[8] = {av0.x, av0.y, av0.z, av0.w, av1.x, av1.y, av1.z, av1.w};
    half8 ah, al;
    #pragma unroll
    for (int j = 0; j < 8; ++j){
      _Float16 h = (_Float16)av[j];
      ah[j] = h;
      al[j] = (_Float16)(av[j] - (float)h);
    }
    half8 bh, bl;
    #pragma unroll
    for (int j = 0; j < 8; ++j){
      float wv = W[(kbase + j) * FOUT + c0 + m16];     // L1-hot (W = 32 KB)
      _Float16 h = (_Float16)wv;
      bh[j] = h;
      bl[j] = (_Float16)(wv - (float)h);
    }
    acc = __builtin_amdgcn_mfma_f32_16x16x32_f16(ah, bh, acc, 0, 0, 0);
    acc = __builtin_amdgcn_mfma_f32_16x16x32_f16(ah, bl, acc, 0, 0, 0);
    acc = __builtin_amdgcn_mfma_f32_16x16x32_f16(al, bh, acc, 0, 0, 0);
  }

  const float a1c = a[c0 + m16];
  const float a2c = a[FOUT + c0 + m16];
  f32x4 p1, p2;
  #pragma unroll
  for (int q = 0; q < 4; ++q){ p1[q] = acc[q] * a1c; p2[q] = acc[q] * a2c; }
  #pragma unroll
  for (int off = 1; off < 16; off <<= 1){
    #pragma unroll
    for (int q = 0; q < 4; ++q){
      p1[q] += __shfl_xor(p1[q], off, 64);
      p2[q] += __shfl_xor(p2[q], off, 64);
    }
  }
  if (m16 == 0){
    #pragma unroll
    for (int q = 0; q < 4; ++q){
      red1[w][g * 4 + q] = p1[q];
      red2[w][g * 4 + q] = p2[q];
    }
  }

  half4 hv;
  #pragma unroll
  for (int q = 0; q < 4; ++q) hv[q] = (_Float16)acc[q];
  size_t idx = (size_t)b * 65536 + (size_t)(j0 >> 5) * 2048
             + (size_t)(c0 + m16) * 32 + (size_t)(j0 & 31) + (size_t)g * 4;
  *(half4*)(hT + idx) = hv;

  __syncthreads();
  if (t < 16){
    s1[i0 + t] = red1[0][t] + red1[1][t] + red1[2][t] + red1[3][t];
    s2[i0 + t] = red2[0][t] + red2[1][t] + red2[2][t] + red2[3][t];
  }
}

// ---------------------------------------------------------------------------
// Kernel 2: fused masked-softmax + MFMA aggregation + ELU — compute-only.
// Reads 2 MB of bitmasks instead of 64 MB of adj (32 B/lane).
// 1024 blocks x 256 thr. Block = (batch, 16-row tile); wave w owns j-range
// [w*256, w*256+256) and all 64 output cols (4 MFMA C tiles).
// Row max via monotone-leaky trick from mask bits + s2 (4 KB LDS).
// ---------------------------------------------------------------------------
__global__ __launch_bounds__(256) void k_attn(const uint32_t* __restrict__ mask,
                                              const _Float16* __restrict__ hT,
                                              const float* __restrict__ s1,
                                              const float* __restrict__ s2,
                                              float* __restrict__ out){
  __shared__ float s2_s[NN];            // 4 KB
  __shared__ float redmax[4][16];
  __shared__ float redl[4][16];
  __shared__ float csum[4][1088];       // ~17 KB

  const int t = threadIdx.x;
  const int w = t >> 6, lane = t & 63;
  const int m16 = lane & 15, g = lane >> 4;
  const int b  = blockIdx.x >> 6;
  const int i0 = (blockIdx.x & 63) * 16;
  const int jb = w * 256;

  // stage this wave's s2 quarter (wave-internal lgkmcnt ordering)
  *(float4*)&s2_s[jb + lane * 4] = *(const float4*)(s2 + b * NN + jb + lane * 4);

  const float s1i = s1[b * NN + i0 + m16];

  // ---- mask words for row i0+m16, this quarter: 8 uint32 = 32 B/lane ----
  const uint32_t* mrow = mask + ((size_t)(b * NN + i0 + m16)) * 32 + w * 8;
  const uint4 mwa = *(const uint4*)mrow;
  const uint4 mwb = *(const uint4*)(mrow + 4);
  const uint32_t mw[8] = {mwa.x, mwa.y, mwa.z, mwa.w, mwb.x, mwb.y, mwb.z, mwb.w};

  // ---- masked neighbor-max of s2 (quarter), then cross-wave reduce ----
  float mxp = -3.0e38f;
  #pragma unroll
  for (int kk = 0; kk < 8; ++kk){
    float4 sA = *(const float4*)&s2_s[jb + kk * 32 + g * 8];
    float4 sB = *(const float4*)&s2_s[jb + kk * 32 + g * 8 + 4];
    const uint32_t bits8 = (mw[kk] >> (g * 8)) & 0xffu;
    const float sv[8] = {sA.x, sA.y, sA.z, sA.w, sB.x, sB.y, sB.z, sB.w};
    #pragma unroll
    for (int u = 0; u < 8; ++u)
      mxp = fmaxf(mxp, ((bits8 >> u) & 1u) ? sv[u] : -3.0e38f);
  }
  mxp = fmaxf(mxp, __shfl_xor(mxp, 16, 64));
  mxp = fmaxf(mxp, __shfl_xor(mxp, 32, 64));
  if (g == 0) redmax[w][m16] = mxp;
  __syncthreads();
  float mxg = fmaxf(fmaxf(redmax[0][m16], redmax[1][m16]),
                    fmaxf(redmax[2][m16], redmax[3][m16]));
  const bool empty = (mxg < -1.0e38f);
  const float xm = s1i + mxg;
  const float mrowmax = fmaxf(xm, ALPHA_S * xm);   // exact row max (monotone)

  // ---- Phase 2: p (A-frag, registers) -> 4 col-tile MFMAs ----
  f32x4 acc0 = {0,0,0,0}, acc1 = {0,0,0,0}, acc2 = {0,0,0,0}, acc3 = {0,0,0,0};
  float psum = 0.f;
  const _Float16* bhp = hT + (size_t)b * 65536 + (size_t)(jb >> 5) * 2048
                      + (size_t)m16 * 32 + (size_t)g * 8;

  #pragma unroll
  for (int kk = 0; kk < 8; ++kk){
    float4 sA = *(const float4*)&s2_s[jb + kk * 32 + g * 8];
    float4 sB = *(const float4*)&s2_s[jb + kk * 32 + g * 8 + 4];
    const uint32_t bits8 = (mw[kk] >> (g * 8)) & 0xffu;
    const float sv[8] = {sA.x, sA.y, sA.z, sA.w, sB.x, sB.y, sB.z, sB.w};
    half8 af;
    #pragma unroll
    for (int u = 0; u < 8; ++u){
      float x = s1i + sv[u];
      float e = fmaxf(x, ALPHA_S * x);
      float p = __expf(e - mrowmax);               // <= 1
      p = ((bits8 >> u) & 1u) ? p : 0.0f;
      p = empty ? 1.0f : p;                        // all-masked row -> uniform
      af[u] = (_Float16)p;
      psum += (float)af[u];                        // denom == numerator dtype
    }
    half8 b0 = *(const half8*)(bhp + kk * 2048);
    half8 b1 = *(const half8*)(bhp + kk * 2048 + 512);
    half8 b2 = *(const half8*)(bhp + kk * 2048 + 1024);
    half8 b3 = *(const half8*)(bhp + kk * 2048 + 1536);
    acc0 = __builtin_amdgcn_mfma_f32_16x16x32_f16(af, b0, acc0, 0, 0, 0);
    acc1 = __builtin_amdgcn_mfma_f32_16x16x32_f16(af, b1, acc1, 0, 0, 0);
    acc2 = __builtin_amdgcn_mfma_f32_16x16x32_f16(af, b2, acc2, 0, 0, 0);
    acc3 = __builtin_amdgcn_mfma_f32_16x16x32_f16(af, b3, acc3, 0, 0, 0);
  }

  // ---- epilogue: cross-wave l and C reduction, ELU, store ----
  psum += __shfl_xor(psum, 16, 64);
  psum += __shfl_xor(psum, 32, 64);
  if (g == 0) redl[w][m16] = psum;

  #pragma unroll
  for (int q = 0; q < 4; ++q){                     // C: row = g*4+q, col = c*16+m16
    csum[w][(g * 4 + q) * 68 +  0 + m16] = acc0[q];
    csum[w][(g * 4 + q) * 68 + 16 + m16] = acc1[q];
    csum[w][(g * 4 + q) * 68 + 32 + m16] = acc2[q];
    csum[w][(g * 4 + q) * 68 + 48 + m16] = acc3[q];
  }
  __syncthreads();

  const int r  = t >> 4;                           // 0..15
  const int c4 = (t & 15) * 4;                     // 0..60
  f32x4 sum = *(const f32x4*)&csum[0][r * 68 + c4];
  sum += *(const f32x4*)&csum[1][r * 68 + c4];
  sum += *(const f32x4*)&csum[2][r * 68 + c4];
  sum += *(const f32x4*)&csum[3][r * 68 + c4];
  const float linv = 1.0f / (redl[0][r] + redl[1][r] + redl[2][r] + redl[3][r]);
  f32x4 o;
  #pragma unroll
  for (int u = 0; u < 4; ++u){
    float v = sum[u] * linv;
    o[u] = v > 0.f ? v : __expf(v) - 1.0f;         // ELU (alpha=1)
  }
  *(f32x4*)(out + ((size_t)(b * NN + i0 + r)) * FOUT + c4) = o;
}

extern "C" void kernel_launch(void* const* d_in, const int* in_sizes, int n_in,
                              void* d_out, int out_size, void* d_ws, size_t ws_size,
                              hipStream_t stream) {
  (void)in_sizes; (void)n_in; (void)out_size; (void)ws_size;
  const float* inp = (const float*)d_in[0];   // (16,1024,128) fp32
  const int*   adj = (const int*)d_in[1];     // (16,1024,1024) int32
  const float* W   = (const float*)d_in[2];   // (128,64) fp32
  const float* a   = (const float*)d_in[3];   // (128,1) fp32
  float* outp = (float*)d_out;                // (16,1024,64) fp32

  _Float16* hT   = (_Float16*)d_ws;                    // 2 MB (hi only)
  float* s1      = (float*)(hT + (size_t)BB * 65536);  // 64 KB
  float* s2      = s1 + BB * NN;                       // 64 KB
  uint32_t* mask = (uint32_t*)(s2 + BB * NN);          // 16384*32 u32 = 2 MB

  k_proj<<<BB * NN / 16, 256, 0, stream>>>(inp, W, a, adj, hT, s1, s2, mask);
  k_attn<<<BB * (NN / 16), 256, 0, stream>>>(mask, hT, s1, s2, outp);
}